// Round 4
// baseline (136.773 us; speedup 1.0000x reference)
//
#include <hip/hip_runtime.h>
#include <math.h>

#define EPS_F 1e-8f
#define NS 10
#define NK 11
#define HDIM 256
#define ROWS_PER_BLOCK 4
#define LOG2E_F 1.44269504088896340736f

// ---- DPP helpers (gfx9/CDNA encodings) ----
// ROW_SHR(n) = 0x110|n, ROW_BCAST15 = 0x142, ROW_BCAST31 = 0x143
template <int CTRL>
__device__ __forceinline__ float dpp_add(float x) {
    int t = __builtin_amdgcn_update_dpp(0, __float_as_int(x), CTRL, 0xf, 0xf, true);
    return x + __int_as_float(t);
}

// full wave64 sum; result valid in lane 63
__device__ __forceinline__ float wave_reduce_to_lane63(float x) {
    x = dpp_add<0x111>(x);   // row_shr:1
    x = dpp_add<0x112>(x);   // row_shr:2
    x = dpp_add<0x114>(x);   // row_shr:4
    x = dpp_add<0x118>(x);   // row_shr:8  -> lane15 of each row has row sum
    x = dpp_add<0x142>(x);   // row_bcast:15
    x = dpp_add<0x143>(x);   // row_bcast:31 -> lane 63 has wave sum
    return x;
}

__device__ __forceinline__ float softplus_f(float x) {
    // log(1 + e^x) = max(x,0) + log(1 + e^{-|x|})  — stable
    float e = __expf(-fabsf(x));
    return fmaxf(x, 0.0f) + __logf(1.0f + e);
}

// tanh via [5/4] Pade on clamped input; max abs err ~1.1e-3 at boundary
__device__ __forceinline__ float pade_tanh_mul(float x, float w) {
    // returns w * tanh~(x)
    float xc = fminf(3.5f, fmaxf(-3.5f, x));
    float y  = xc * xc;
    float num = fmaf(y, fmaf(y, 1.0582011e-3f, 1.1111111e-1f), 1.0f);
    float den = fmaf(y, fmaf(y, 1.5873016e-2f, 4.4444445e-1f), 1.0f);
    float r = __builtin_amdgcn_rcpf(den);
    return (w * xc) * (num * r);
}

__global__ __launch_bounds__(256) void intensity_loss_kernel(
    const float* __restrict__ duration,   // [B]
    const float* __restrict__ cx,         // [B,H]
    const float* __restrict__ cbarx,      // [B,H]
    const float* __restrict__ deltx,      // [B,H]
    const float* __restrict__ ox,         // [B,H]
    const float* __restrict__ W,          // [H]
    const float* __restrict__ bptr,       // [1]
    const float* __restrict__ u,          // [NS,B]
    float* __restrict__ out,              // [B]
    int B)
{
    const int lane = threadIdx.x & 63;
    // wave index is wave-uniform by construction; make it PROVABLY uniform so
    // row-indexed loads (duration, u) become scalar s_loads.
    const int wave = __builtin_amdgcn_readfirstlane(threadIdx.x >> 6);
    const int row  = blockIdx.x * ROWS_PER_BLOCK + wave;
    if (row >= B) return;

    const size_t base = (size_t)row * HDIM + (size_t)(lane << 2);

    const float4 vcx = *reinterpret_cast<const float4*>(cx    + base);
    const float4 vcb = *reinterpret_cast<const float4*>(cbarx + base);
    const float4 vdl = *reinterpret_cast<const float4*>(deltx + base);
    const float4 vox = *reinterpret_cast<const float4*>(ox    + base);
    const float4 vw  = *reinterpret_cast<const float4*>(W + (lane << 2));

    const float dur = duration[row];      // scalar load (row uniform)
    const float bb  = bptr[0];

    float t[NK];
    t[0] = dur;
#pragma unroll
    for (int s = 0; s < NS; ++s)
        t[s + 1] = u[(size_t)s * (size_t)B + (size_t)row] * dur;  // scalar loads

    // per-row invariants; prescale delta by -log2(e) so decay = exp2(dlg * t)
    float cb[4]  = {vcb.x, vcb.y, vcb.z, vcb.w};
    float dx[4]  = {vcx.x - vcb.x, vcx.y - vcb.y, vcx.z - vcb.z, vcx.w - vcb.w};
    float dlg[4] = {-vdl.x * LOG2E_F, -vdl.y * LOG2E_F, -vdl.z * LOG2E_F, -vdl.w * LOG2E_F};
    float ow[4]  = {vox.x * vw.x, vox.y * vw.y, vox.z * vw.z, vox.w * vw.w};

    float acc[NK];
#pragma unroll
    for (int k = 0; k < NK; ++k) {
        const float tk = t[k];
        float a = 0.0f;
#pragma unroll
        for (int j = 0; j < 4; ++j) {
            float decay = exp2f(dlg[j] * tk);          // v_mul + v_exp_f32
            float c_t   = fmaf(dx[j], decay, cb[j]);
            a += pade_tanh_mul(c_t, ow[j]);
        }
        acc[k] = a;
    }

    // 11 independent DPP reduction chains — pure VALU, no LDS pipe, no waits
#pragma unroll
    for (int k = 0; k < NK; ++k)
        acc[k] = wave_reduce_to_lane63(acc[k]);

    // gather the 11 sums: readlane -> SGPR (uniform), select into lane k
    float zsel = 0.0f;
#pragma unroll
    for (int k = 0; k < NK; ++k) {
        float s = __int_as_float(__builtin_amdgcn_readlane(__float_as_int(acc[k]), 63));
        zsel = (lane == k) ? s : zsel;   // v_cmp + v_cndmask (SGPR operand)
    }

    // one wave-wide softplus covers all 11 values
    float sp = softplus_f(zsel + bb);
    const float scale = dur * (1.0f / (float)NS);

    float contrib = (lane == 0) ? (-__logf(sp + EPS_F))
                  : ((lane <= NS) ? sp * scale : 0.0f);

    // lanes 0..10 live in row 0 -> 4-step row reduce, sum lands in lane 15
    contrib = dpp_add<0x111>(contrib);
    contrib = dpp_add<0x112>(contrib);
    contrib = dpp_add<0x114>(contrib);
    contrib = dpp_add<0x118>(contrib);

    if (lane == 15) out[row] = contrib;
}

extern "C" void kernel_launch(void* const* d_in, const int* in_sizes, int n_in,
                              void* d_out, int out_size, void* d_ws, size_t ws_size,
                              hipStream_t stream) {
    const float* duration = (const float*)d_in[0];
    const float* cx       = (const float*)d_in[1];
    const float* cbarx    = (const float*)d_in[2];
    const float* deltx    = (const float*)d_in[3];
    const float* ox       = (const float*)d_in[4];
    const float* W        = (const float*)d_in[5];
    const float* b        = (const float*)d_in[6];
    const float* u        = (const float*)d_in[7];
    float* out            = (float*)d_out;

    const int B = in_sizes[0];           // 65536
    const int grid = (B + ROWS_PER_BLOCK - 1) / ROWS_PER_BLOCK;

    intensity_loss_kernel<<<grid, 256, 0, stream>>>(
        duration, cx, cbarx, deltx, ox, W, b, u, out, B);
}

// Round 5
// 110.770 us; speedup vs baseline: 1.2348x; 1.2348x over previous
//
#include <hip/hip_runtime.h>
#include <math.h>

#define EPS_F 1e-8f
#define NS 10
#define NK 11
#define HDIM 256
#define ROWS_PER_BLOCK 4
#define LOG2E_F 1.44269504088896340736f

__device__ __forceinline__ float softplus_f(float x) {
    // log(1 + e^x) = max(x,0) + log(1 + e^{-|x|})  — stable
    float e = __expf(-fabsf(x));
    return fmaxf(x, 0.0f) + __logf(1.0f + e);
}

// tanh via [5/4] Pade on clamped input: x(945+105y+y^2)/(945+420y+15y^2), y=x^2
// clamped to |x|<=3.5 ; max abs error ~1.1e-3 (boundary), ~3e-4 typical.
__device__ __forceinline__ float pade_tanh(float x) {
    float xc = fminf(3.5f, fmaxf(-3.5f, x));   // -> v_med3_f32
    float y  = xc * xc;
    float num = fmaf(y, fmaf(y, 1.0582011e-3f, 1.1111111e-1f), 1.0f);
    float den = fmaf(y, fmaf(y, 1.5873016e-2f, 4.4444445e-1f), 1.0f);
    return (xc * num) * __builtin_amdgcn_rcpf(den);
}

// min 4 waves/EU -> VGPR cap 128: stop the compiler rematerializing per-row
// invariants to hit 8 waves/SIMD (24-VGPR codegen) we don't need.
__global__ __launch_bounds__(256, 4) void intensity_loss_kernel(
    const float* __restrict__ duration,   // [B]
    const float* __restrict__ cx,         // [B,H]
    const float* __restrict__ cbarx,      // [B,H]
    const float* __restrict__ deltx,      // [B,H]
    const float* __restrict__ ox,         // [B,H]
    const float* __restrict__ W,          // [H]
    const float* __restrict__ bptr,       // [1]
    const float* __restrict__ u,          // [NS,B]
    float* __restrict__ out,              // [B]
    int B)
{
    const int wave = threadIdx.x >> 6;
    const int lane = threadIdx.x & 63;
    const int row  = blockIdx.x * ROWS_PER_BLOCK + wave;
    if (row >= B) return;

    const size_t base = (size_t)row * HDIM + (size_t)(lane << 2);

    const float4 vcx = *reinterpret_cast<const float4*>(cx    + base);
    const float4 vcb = *reinterpret_cast<const float4*>(cbarx + base);
    const float4 vdl = *reinterpret_cast<const float4*>(deltx + base);
    const float4 vox = *reinterpret_cast<const float4*>(ox    + base);
    const float4 vw  = *reinterpret_cast<const float4*>(W + (lane << 2));

    const float dur = duration[row];

    // all t-values up front (loads overlap)
    float t[NK];
    t[0] = dur;
#pragma unroll
    for (int s = 0; s < NS; ++s)
        t[s + 1] = u[(size_t)s * (size_t)B + (size_t)row] * dur;

    // per-row invariants; prescale delta by -log2(e) so decay = exp2(dlg * t)
    float cb[4]  = {vcb.x, vcb.y, vcb.z, vcb.w};
    float dx[4]  = {vcx.x - vcb.x, vcx.y - vcb.y, vcx.z - vcb.z, vcx.w - vcb.w};
    float dlg[4] = {-vdl.x * LOG2E_F, -vdl.y * LOG2E_F, -vdl.z * LOG2E_F, -vdl.w * LOG2E_F};
    float ow[4]  = {vox.x * vw.x, vox.y * vw.y, vox.z * vw.z, vox.w * vw.w};

    float acc[NK];
#pragma unroll
    for (int k = 0; k < NK; ++k) {
        const float tk = t[k];
        float a = 0.0f;
#pragma unroll
        for (int j = 0; j < 4; ++j) {
            float decay = exp2f(dlg[j] * tk);          // v_mul + v_exp_f32
            float c_t   = fmaf(dx[j], decay, cb[j]);
            a = fmaf(ow[j], pade_tanh(c_t), a);
        }
        acc[k] = a;
    }

    // batched butterfly: issue all 11 shuffles per step so latencies overlap
#pragma unroll
    for (int off = 32; off > 0; off >>= 1) {
        float tmp[NK];
#pragma unroll
        for (int k = 0; k < NK; ++k) tmp[k] = __shfl_xor(acc[k], off, 64);
#pragma unroll
        for (int k = 0; k < NK; ++k) acc[k] += tmp[k];
    }

    // wave-parallel epilogue: lane k owns acc[k] (k=0..10)
    const float bb = bptr[0];
    float z = acc[0];
#pragma unroll
    for (int k = 1; k < NK; ++k) z = (lane == k) ? acc[k] : z;

    float sp   = softplus_f(z + bb);
    float nllv = -__logf(sp + EPS_F);
    const float scale = dur * (1.0f / (float)NS);

    float contrib = (lane == 0) ? nllv
                  : ((lane <= NS) ? sp * scale : 0.0f);
#pragma unroll
    for (int off = 32; off > 0; off >>= 1)
        contrib += __shfl_xor(contrib, off, 64);

    if (lane == 0) out[row] = contrib;
}

extern "C" void kernel_launch(void* const* d_in, const int* in_sizes, int n_in,
                              void* d_out, int out_size, void* d_ws, size_t ws_size,
                              hipStream_t stream) {
    const float* duration = (const float*)d_in[0];
    const float* cx       = (const float*)d_in[1];
    const float* cbarx    = (const float*)d_in[2];
    const float* deltx    = (const float*)d_in[3];
    const float* ox       = (const float*)d_in[4];
    const float* W        = (const float*)d_in[5];
    const float* b        = (const float*)d_in[6];
    const float* u        = (const float*)d_in[7];
    float* out            = (float*)d_out;

    const int B = in_sizes[0];           // 65536
    const int grid = (B + ROWS_PER_BLOCK - 1) / ROWS_PER_BLOCK;

    intensity_loss_kernel<<<grid, 256, 0, stream>>>(
        duration, cx, cbarx, deltx, ox, W, b, u, out, B);
}

// Round 6
// 105.942 us; speedup vs baseline: 1.2910x; 1.0456x over previous
//
#include <hip/hip_runtime.h>
#include <math.h>

#define EPS_F 1e-8f
#define NS 10
#define NK 11
#define HDIM 256
#define ROWS_PER_BLOCK 4
#define LOG2E_F 1.44269504088896340736f

__device__ __forceinline__ float softplus_f(float x) {
    // log(1 + e^x) = max(x,0) + log(1 + e^{-|x|})  — stable
    float e = __expf(-fabsf(x));
    return fmaxf(x, 0.0f) + __logf(1.0f + e);
}

// tanh via [5/4] Pade on clamped input: x(945+105y+y^2)/(945+420y+15y^2), y=x^2
// clamped to |x|<=3.5 ; max abs error ~1.1e-3 (boundary), ~3e-4 typical.
__device__ __forceinline__ float pade_tanh(float x) {
    float xc = fminf(3.5f, fmaxf(-3.5f, x));
    float y  = xc * xc;
    float num = fmaf(y, fmaf(y, 1.0582011e-3f, 1.1111111e-1f), 1.0f);
    float den = fmaf(y, fmaf(y, 1.5873016e-2f, 4.4444445e-1f), 1.0f);
    return (xc * num) * __builtin_amdgcn_rcpf(den);
}

__global__ __launch_bounds__(256, 4) void intensity_loss_kernel(
    const float* __restrict__ duration,   // [B]
    const float* __restrict__ cx,         // [B,H]
    const float* __restrict__ cbarx,      // [B,H]
    const float* __restrict__ deltx,      // [B,H]
    const float* __restrict__ ox,         // [B,H]
    const float* __restrict__ W,          // [H]
    const float* __restrict__ bptr,       // [1]
    const float* __restrict__ u,          // [NS,B]
    float* __restrict__ out,              // [B]
    int B)
{
    const int lane = threadIdx.x & 63;
    // provably wave-uniform row -> duration/u loads become scalar s_loads,
    // and their values live in SGPRs (frees 11 VGPRs vs a t[] array).
    const int wave = __builtin_amdgcn_readfirstlane(threadIdx.x >> 6);
    const int row  = blockIdx.x * ROWS_PER_BLOCK + wave;
    if (row >= B) return;

    const size_t base = (size_t)row * HDIM + (size_t)(lane << 2);

    const float4 vcx = *reinterpret_cast<const float4*>(cx    + base);
    const float4 vcb = *reinterpret_cast<const float4*>(cbarx + base);
    const float4 vdl = *reinterpret_cast<const float4*>(deltx + base);
    const float4 vox = *reinterpret_cast<const float4*>(ox    + base);
    const float4 vw  = *reinterpret_cast<const float4*>(W + (lane << 2));

    const float dur = duration[row];      // scalar load (row uniform)
    const float bb  = bptr[0];            // scalar load

    // u values, SGPR-resident; slot 0 is the observed-event eval (t = dur, u=1)
    float us[NK];
    us[0] = 1.0f;
#pragma unroll
    for (int s = 0; s < NS; ++s)
        us[s + 1] = u[(size_t)s * (size_t)B + (size_t)row];   // s_loads

    // per-row invariants; fold (-log2e * dur) into delta so the inner
    // exponent is a single v_mul with an SGPR operand + raw v_exp_f32.
    const float nld = -LOG2E_F * dur;
    float cb[4]   = {vcb.x, vcb.y, vcb.z, vcb.w};
    float dx[4]   = {vcx.x - vcb.x, vcx.y - vcb.y, vcx.z - vcb.z, vcx.w - vcb.w};
    float dlgd[4] = {vdl.x * nld, vdl.y * nld, vdl.z * nld, vdl.w * nld};
    float ow[4]   = {vox.x * vw.x, vox.y * vw.y, vox.z * vw.z, vox.w * vw.w};

    float acc[NK];
#pragma unroll
    for (int k = 0; k < NK; ++k) {
        const float uk = us[k];
        float a = 0.0f;
#pragma unroll
        for (int j = 0; j < 4; ++j) {
            float decay = __builtin_amdgcn_exp2f(dlgd[j] * uk);  // v_mul + v_exp
            float c_t   = fmaf(dx[j], decay, cb[j]);
            a = fmaf(ow[j], pade_tanh(c_t), a);
        }
        acc[k] = a;
    }

    // batched butterfly: issue all 11 shuffles per step so latencies overlap
#pragma unroll
    for (int off = 32; off > 0; off >>= 1) {
        float tmp[NK];
#pragma unroll
        for (int k = 0; k < NK; ++k) tmp[k] = __shfl_xor(acc[k], off, 64);
#pragma unroll
        for (int k = 0; k < NK; ++k) acc[k] += tmp[k];
    }

    // wave-parallel epilogue: lane k owns acc[k] (k=0..10)
    float z = acc[0];
#pragma unroll
    for (int k = 1; k < NK; ++k) z = (lane == k) ? acc[k] : z;

    float sp   = softplus_f(z + bb);
    float nllv = -__logf(sp + EPS_F);
    const float scale = dur * (1.0f / (float)NS);

    float contrib = (lane == 0) ? nllv
                  : ((lane <= NS) ? sp * scale : 0.0f);

    // lanes 0..10 live within one 16-lane row -> 4 steps suffice
#pragma unroll
    for (int off = 8; off > 0; off >>= 1)
        contrib += __shfl_xor(contrib, off, 64);

    if (lane == 0) out[row] = contrib;
}

extern "C" void kernel_launch(void* const* d_in, const int* in_sizes, int n_in,
                              void* d_out, int out_size, void* d_ws, size_t ws_size,
                              hipStream_t stream) {
    const float* duration = (const float*)d_in[0];
    const float* cx       = (const float*)d_in[1];
    const float* cbarx    = (const float*)d_in[2];
    const float* deltx    = (const float*)d_in[3];
    const float* ox       = (const float*)d_in[4];
    const float* W        = (const float*)d_in[5];
    const float* b        = (const float*)d_in[6];
    const float* u        = (const float*)d_in[7];
    float* out            = (float*)d_out;

    const int B = in_sizes[0];           // 65536
    const int grid = (B + ROWS_PER_BLOCK - 1) / ROWS_PER_BLOCK;

    intensity_loss_kernel<<<grid, 256, 0, stream>>>(
        duration, cx, cbarx, deltx, ox, W, b, u, out, B);
}

// Round 7
// 87.582 us; speedup vs baseline: 1.5617x; 1.2096x over previous
//
#include <hip/hip_runtime.h>
#include <math.h>

#define EPS_F 1e-8f
#define NS 10
#define NK 11
#define HDIM 256
#define ROWS_PER_BLOCK 4
#define LOG2E_F 1.44269504088896340736f

// Pade [5/4] tanh coefficients: tanh x ~= x(1 + y/9 + y^2/945)/(1 + 4y/9 + y^2/63)
#define PA1 1.1111111e-1f
#define PA2 1.0582011e-3f
#define PB1 4.4444445e-1f
#define PB2 1.5873016e-2f

__device__ __forceinline__ float softplus_f(float x) {
    // log(1 + e^x) = max(x,0) + log(1 + e^{-|x|})  — stable
    float e = __expf(-fabsf(x));
    return fmaxf(x, 0.0f) + __logf(1.0f + e);
}

__global__ __launch_bounds__(256) void intensity_loss_kernel(
    const float* __restrict__ duration,   // [B]
    const float* __restrict__ cx,         // [B,H]
    const float* __restrict__ cbarx,      // [B,H]
    const float* __restrict__ deltx,      // [B,H]
    const float* __restrict__ ox,         // [B,H]
    const float* __restrict__ W,          // [H]
    const float* __restrict__ bptr,       // [1]
    const float* __restrict__ u,          // [NS,B]
    float* __restrict__ out,              // [B]
    int B)
{
    const int wave = threadIdx.x >> 6;
    const int lane = threadIdx.x & 63;
    const int row  = blockIdx.x * ROWS_PER_BLOCK + wave;
    if (row >= B) return;

    const size_t base = (size_t)row * HDIM + (size_t)(lane << 2);

    const float4 vcx = *reinterpret_cast<const float4*>(cx    + base);
    const float4 vcb = *reinterpret_cast<const float4*>(cbarx + base);
    const float4 vdl = *reinterpret_cast<const float4*>(deltx + base);
    const float4 vox = *reinterpret_cast<const float4*>(ox    + base);
    const float4 vw  = *reinterpret_cast<const float4*>(W + (lane << 2));

    const float dur = duration[row];

    // all t-values up front, vector loads (R2-proven; scalar s_loads regressed in R6)
    float t[NK];
    t[0] = dur;
#pragma unroll
    for (int s = 0; s < NS; ++s)
        t[s + 1] = u[(size_t)s * (size_t)B + (size_t)row] * dur;

    // per-row invariants; fold -log2(e) into delta: decay = exp2(dlg * t)
    float cb[4]  = {vcb.x, vcb.y, vcb.z, vcb.w};
    float dx[4]  = {vcx.x - vcb.x, vcx.y - vcb.y, vcx.z - vcb.z, vcx.w - vcb.w};
    float dlg[4] = {-vdl.x * LOG2E_F, -vdl.y * LOG2E_F, -vdl.z * LOG2E_F, -vdl.w * LOG2E_F};
    float ow[4]  = {vox.x * vw.x, vox.y * vw.y, vox.z * vw.z, vox.w * vw.w};

    float acc[NK];
#pragma unroll
    for (int k = 0; k < NK; ++k) {
        const float tk = t[k];
        float a = 0.0f;
#pragma unroll
        for (int jj = 0; jj < 4; jj += 2) {
            // two element-evals sharing ONE v_rcp via rcp(d0*d1)
            float e0 = __builtin_amdgcn_exp2f(dlg[jj]     * tk);  // v_mul + v_exp
            float e1 = __builtin_amdgcn_exp2f(dlg[jj + 1] * tk);
            float c0 = fmaf(dx[jj],     e0, cb[jj]);
            float c1 = fmaf(dx[jj + 1], e1, cb[jj + 1]);
            // unclamped Pade[5/4]: |c_t| <= max(|cx|,|cbarx|) (convex combo), ~<=5.8
            float y0 = c0 * c0,  y1 = c1 * c1;
            float n0 = fmaf(y0, fmaf(y0, PA2, PA1), 1.0f);
            float n1 = fmaf(y1, fmaf(y1, PA2, PA1), 1.0f);
            float d0 = fmaf(y0, fmaf(y0, PB2, PB1), 1.0f);
            float d1 = fmaf(y1, fmaf(y1, PB2, PB1), 1.0f);
            float xn0 = (ow[jj]     * c0) * n0;     // w*o*x*num
            float xn1 = (ow[jj + 1] * c1) * n1;
            float R  = __builtin_amdgcn_rcpf(d0 * d1);
            a = fmaf(xn0, R * d1, a);               // xn0 / d0
            a = fmaf(xn1, R * d0, a);               // xn1 / d1
        }
        acc[k] = a;
    }

    // batched butterfly: issue all 11 shuffles per step so latencies overlap
#pragma unroll
    for (int off = 32; off > 0; off >>= 1) {
        float tmp[NK];
#pragma unroll
        for (int k = 0; k < NK; ++k) tmp[k] = __shfl_xor(acc[k], off, 64);
#pragma unroll
        for (int k = 0; k < NK; ++k) acc[k] += tmp[k];
    }

    // wave-parallel epilogue: lane k owns acc[k] (k=0..10)
    const float bb = bptr[0];
    float z = acc[0];
#pragma unroll
    for (int k = 1; k < NK; ++k) z = (lane == k) ? acc[k] : z;

    float sp   = softplus_f(z + bb);
    float nllv = -__logf(sp + EPS_F);
    const float scale = dur * (1.0f / (float)NS);

    float contrib = (lane == 0) ? nllv
                  : ((lane <= NS) ? sp * scale : 0.0f);

    // lanes 0..10 live within one 16-lane row -> 4 steps suffice
#pragma unroll
    for (int off = 8; off > 0; off >>= 1)
        contrib += __shfl_xor(contrib, off, 64);

    if (lane == 0) out[row] = contrib;
}

extern "C" void kernel_launch(void* const* d_in, const int* in_sizes, int n_in,
                              void* d_out, int out_size, void* d_ws, size_t ws_size,
                              hipStream_t stream) {
    const float* duration = (const float*)d_in[0];
    const float* cx       = (const float*)d_in[1];
    const float* cbarx    = (const float*)d_in[2];
    const float* deltx    = (const float*)d_in[3];
    const float* ox       = (const float*)d_in[4];
    const float* W        = (const float*)d_in[5];
    const float* b        = (const float*)d_in[6];
    const float* u        = (const float*)d_in[7];
    float* out            = (float*)d_out;

    const int B = in_sizes[0];           // 65536
    const int grid = (B + ROWS_PER_BLOCK - 1) / ROWS_PER_BLOCK;

    intensity_loss_kernel<<<grid, 256, 0, stream>>>(
        duration, cx, cbarx, deltx, ox, W, b, u, out, B);
}

// Round 8
// 85.828 us; speedup vs baseline: 1.5936x; 1.0204x over previous
//
#include <hip/hip_runtime.h>
#include <math.h>

#define EPS_F 1e-8f
#define NS 10
#define NK 11
#define HDIM 256
#define ROWS_PER_BLOCK 4
#define LOG2E_F 1.44269504088896340736f

// Pade [5/4] tanh coefficients: tanh x ~= x(1 + y/9 + y^2/945)/(1 + 4y/9 + y^2/63)
#define PA1 1.1111111e-1f
#define PA2 1.0582011e-3f
#define PB1 4.4444445e-1f
#define PB2 1.5873016e-2f

// Pin a value into a VGPR: zero-instruction allocation constraint that the
// register allocator cannot rematerialize past (anti-remat).
#define PIN(x) asm volatile("" : "+v"(x))

__device__ __forceinline__ float softplus_f(float x) {
    // log(1 + e^x) = max(x,0) + log(1 + e^{-|x|})  — stable
    float e = __expf(-fabsf(x));
    return fmaxf(x, 0.0f) + __logf(1.0f + e);
}

__global__ __launch_bounds__(256) void intensity_loss_kernel(
    const float* __restrict__ duration,   // [B]
    const float* __restrict__ cx,         // [B,H]
    const float* __restrict__ cbarx,      // [B,H]
    const float* __restrict__ deltx,      // [B,H]
    const float* __restrict__ ox,         // [B,H]
    const float* __restrict__ W,          // [H]
    const float* __restrict__ bptr,       // [1]
    const float* __restrict__ u,          // [NS,B]
    float* __restrict__ out,              // [B]
    int B)
{
    const int wave = threadIdx.x >> 6;
    const int lane = threadIdx.x & 63;
    const int row  = blockIdx.x * ROWS_PER_BLOCK + wave;
    if (row >= B) return;

    const size_t base = (size_t)row * HDIM + (size_t)(lane << 2);

    const float4 vcx = *reinterpret_cast<const float4*>(cx    + base);
    const float4 vcb = *reinterpret_cast<const float4*>(cbarx + base);
    const float4 vdl = *reinterpret_cast<const float4*>(deltx + base);
    const float4 vox = *reinterpret_cast<const float4*>(ox    + base);
    const float4 vw  = *reinterpret_cast<const float4*>(W + (lane << 2));

    const float dur = duration[row];

    // u samples (vector loads, R7-proven path; scalar s_loads regressed in R6)
    float us[NS];
#pragma unroll
    for (int s = 0; s < NS; ++s)
        us[s] = u[(size_t)s * (size_t)B + (size_t)row];

    // per-row invariants; fold (-log2e * dur) into delta so the inner
    // exponent is one v_mul: dlgd[j] * u_k   (k=0 uses u == 1 implicitly)
    const float nld = -LOG2E_F * dur;
    float cb[4]   = {vcb.x, vcb.y, vcb.z, vcb.w};
    float dx[4]   = {vcx.x - vcb.x, vcx.y - vcb.y, vcx.z - vcb.z, vcx.w - vcb.w};
    float dlgd[4] = {vdl.x * nld, vdl.y * nld, vdl.z * nld, vdl.w * nld};
    float ow[4]   = {vox.x * vw.x, vox.y * vw.y, vox.z * vw.z, vox.w * vw.w};

    // pin all 26 per-row invariants into VGPRs so the 24-VGPR remat schedule
    // is impossible; live set ~40 -> allocator must widen
#pragma unroll
    for (int j = 0; j < 4; ++j) {
        PIN(cb[j]); PIN(dx[j]); PIN(dlgd[j]); PIN(ow[j]);
    }
#pragma unroll
    for (int s = 0; s < NS; ++s) PIN(us[s]);

    float acc[NK];
#pragma unroll
    for (int k = 0; k < NK; ++k) {
        float a = 0.0f;
#pragma unroll
        for (int jj = 0; jj < 4; jj += 2) {
            // exponent: k=0 is the observed-event eval (t = dur, u = 1)
            float x0 = (k == 0) ? dlgd[jj]     : dlgd[jj]     * us[k - 1];
            float x1 = (k == 0) ? dlgd[jj + 1] : dlgd[jj + 1] * us[k - 1];
            float e0 = __builtin_amdgcn_exp2f(x0);
            float e1 = __builtin_amdgcn_exp2f(x1);
            float c0 = fmaf(dx[jj],     e0, cb[jj]);
            float c1 = fmaf(dx[jj + 1], e1, cb[jj + 1]);
            // unclamped Pade[5/4], two evals share ONE v_rcp via rcp(d0*d1)
            float y0 = c0 * c0,  y1 = c1 * c1;
            float n0 = fmaf(y0, fmaf(y0, PA2, PA1), 1.0f);
            float n1 = fmaf(y1, fmaf(y1, PA2, PA1), 1.0f);
            float d0 = fmaf(y0, fmaf(y0, PB2, PB1), 1.0f);
            float d1 = fmaf(y1, fmaf(y1, PB2, PB1), 1.0f);
            float xn0 = (ow[jj]     * c0) * n0;     // w*o*x*num
            float xn1 = (ow[jj + 1] * c1) * n1;
            float R  = __builtin_amdgcn_rcpf(d0 * d1);
            a = fmaf(xn0, R * d1, a);               // xn0 / d0
            a = fmaf(xn1, R * d0, a);               // xn1 / d1
        }
        acc[k] = a;
    }

    // batched butterfly: issue all 11 shuffles per step so latencies overlap
#pragma unroll
    for (int off = 32; off > 0; off >>= 1) {
        float tmp[NK];
#pragma unroll
        for (int k = 0; k < NK; ++k) tmp[k] = __shfl_xor(acc[k], off, 64);
#pragma unroll
        for (int k = 0; k < NK; ++k) acc[k] += tmp[k];
    }

    // wave-parallel epilogue: lane k owns acc[k] (k=0..10)
    const float bb = bptr[0];
    float z = acc[0];
#pragma unroll
    for (int k = 1; k < NK; ++k) z = (lane == k) ? acc[k] : z;

    float sp   = softplus_f(z + bb);
    float nllv = -__logf(sp + EPS_F);
    const float scale = dur * (1.0f / (float)NS);

    float contrib = (lane == 0) ? nllv
                  : ((lane <= NS) ? sp * scale : 0.0f);

    // lanes 0..10 live within one 16-lane row -> 4 steps suffice
#pragma unroll
    for (int off = 8; off > 0; off >>= 1)
        contrib += __shfl_xor(contrib, off, 64);

    if (lane == 0) out[row] = contrib;
}

extern "C" void kernel_launch(void* const* d_in, const int* in_sizes, int n_in,
                              void* d_out, int out_size, void* d_ws, size_t ws_size,
                              hipStream_t stream) {
    const float* duration = (const float*)d_in[0];
    const float* cx       = (const float*)d_in[1];
    const float* cbarx    = (const float*)d_in[2];
    const float* deltx    = (const float*)d_in[3];
    const float* ox       = (const float*)d_in[4];
    const float* W        = (const float*)d_in[5];
    const float* b        = (const float*)d_in[6];
    const float* u        = (const float*)d_in[7];
    float* out            = (float*)d_out;

    const int B = in_sizes[0];           // 65536
    const int grid = (B + ROWS_PER_BLOCK - 1) / ROWS_PER_BLOCK;

    intensity_loss_kernel<<<grid, 256, 0, stream>>>(
        duration, cx, cbarx, deltx, ox, W, b, u, out, B);
}